// Round 1
// baseline (274.865 us; speedup 1.0000x reference)
//
#include <hip/hip_runtime.h>
#include <stdint.h>

#define HEADS 8
#define DH    32
#define BSZ   8
#define HALO  3
#define WIN   14
#define NKEY  196
#define CIN   256
#define IMG   128
#define HWPIX 16384
#define MQKV  768         // 8 heads x (q32 + k32 + v32), head-blocked
#define SCALE 0.17677669529663689f  // 32^-0.5

#define KS_STRIDE 36      // shorts, 72 B rows (8B aligned, l15*18dw: 16 distinct banks)
#define VT_STRIDE 212     // shorts (106 dw == 2 mod 4; reads conflict-free)
#define PQ_STRIDE 120     // shorts (16B-mult rows; q*60dw -> 2-way max)
#define QB_STRIDE 68      // shorts (8B-mult; q*34dw -> 16 distinct banks)

typedef short bf16x8 __attribute__((ext_vector_type(8)));
typedef short bf16x4 __attribute__((ext_vector_type(4)));
typedef float f32x4  __attribute__((ext_vector_type(4)));

#define AS1 __attribute__((address_space(1)))
#define AS3 __attribute__((address_space(3)))

__device__ __forceinline__ void gl_lds16(const void* g, void* l) {
  __builtin_amdgcn_global_load_lds((AS1 const unsigned int*)g,
                                   (AS3 unsigned int*)l, 16, 0, 0);
}

__device__ __forceinline__ float bf2f(unsigned short s){ return __uint_as_float(((unsigned int)s) << 16); }
__device__ __forceinline__ unsigned short f2bf(float f){        // RNE
  unsigned int u = __float_as_uint(f);
  u += 0x7fffu + ((u >> 16) & 1u);
  return (unsigned short)(u >> 16);
}

// 8-short fragment from two 8B-aligned LDS halves
__device__ __forceinline__ bf16x8 ld2(const unsigned short* p) {
  bf16x4 a = *(const bf16x4*)p;
  bf16x4 b = *(const bf16x4*)(p + 4);
  bf16x8 r;
  r[0]=a[0]; r[1]=a[1]; r[2]=a[2]; r[3]=a[3];
  r[4]=b[0]; r[5]=b[1]; r[6]=b[2]; r[7]=b[3];
  return r;
}

__device__ __forceinline__ void st_bf4(unsigned short* p, f32x4 c) {
  ushort4 o;
  o.x = f2bf(c[0]); o.y = f2bf(c[1]); o.z = f2bf(c[2]); o.w = f2bf(c[3]);
  *(ushort4*)p = o;
}

// ---------------------------------------------------------------------------
// W fp32 -> bf16, head-blocked rows: m = h*96 + d; d<32 -> wq[h*32+d],
// d in [32,96) -> wkv[h*64 + d-32].
// ---------------------------------------------------------------------------
__global__ void convw_kernel(const float* __restrict__ wq,
                             const float* __restrict__ wkv,
                             unsigned short* __restrict__ Wb)
{
  int idx = blockIdx.x * 256 + threadIdx.x;      // 768 rows x 64 float4
  int m = idx >> 6, c4 = idx & 63;
  int h = m / 96, d = m - h * 96;
  const float* src = (d < 32) ? wq  + (size_t)(h * 32 + d) * CIN
                              : wkv + (size_t)(h * 64 + d - 32) * CIN;
  float4 v = *(const float4*)(src + c4 * 4);
  ushort4 o;
  o.x = f2bf(v.x); o.y = f2bf(v.y); o.z = f2bf(v.z); o.w = f2bf(v.w);
  *(ushort4*)(Wb + (size_t)m * CIN + c4 * 4) = o;
}

// ---------------------------------------------------------------------------
// rel tables -> bf16 [64][32]: rows 0..26 hrel, 27..31 zero, 32..58 wrel, 59..63 zero
// ---------------------------------------------------------------------------
__global__ void convrel_kernel(const float* __restrict__ hrel,
                               const float* __restrict__ wrel,
                               unsigned short* __restrict__ relb)
{
  int idx = blockIdx.x * 256 + threadIdx.x;      // 2048
  int r = idx >> 5, c = idx & 31;
  float v = 0.f;
  if (r < 27) v = hrel[r * 32 + c];
  else if (r >= 32 && r < 59) v = wrel[(r - 32) * 32 + c];
  relb[idx] = f2bf(v);
}

// ---------------------------------------------------------------------------
// x [chunk][256][16384] f32 -> xb [chunk][16384][256] bf16
// ---------------------------------------------------------------------------
__global__ __launch_bounds__(256)
void convx_kernel(const float* __restrict__ x, unsigned short* __restrict__ xb)
{
  __shared__ unsigned short T[64 * 264];
  const int tid = threadIdx.x;
  const int p0 = blockIdx.x * 64;
  const float* xin = x + (size_t)blockIdx.y * CIN * HWPIX;
  unsigned short* xo = xb + ((size_t)blockIdx.y * HWPIX + p0) * CIN;

  for (int idx = tid; idx < 2048; idx += 256) {
    int cp = idx >> 4, f = idx & 15;
    const float* r0 = xin + (size_t)(2 * cp) * HWPIX + p0 + f * 4;
    float4 a = *(const float4*)r0;
    float4 b = *(const float4*)(r0 + HWPIX);
    unsigned short* tp = T + (4 * f) * 264 + 2 * cp;
    *(unsigned int*)(tp      ) = (unsigned int)f2bf(a.x) | ((unsigned int)f2bf(b.x) << 16);
    *(unsigned int*)(tp + 264) = (unsigned int)f2bf(a.y) | ((unsigned int)f2bf(b.y) << 16);
    *(unsigned int*)(tp + 528) = (unsigned int)f2bf(a.z) | ((unsigned int)f2bf(b.z) << 16);
    *(unsigned int*)(tp + 792) = (unsigned int)f2bf(a.w) | ((unsigned int)f2bf(b.w) << 16);
  }
  __syncthreads();
  for (int idx = tid; idx < 2048; idx += 256) {
    int p = idx >> 5, u = idx & 31;
    *(uint4*)(xo + (size_t)p * CIN + u * 8) = *(const uint4*)(T + p * 264 + u * 8);
  }
}

// ---------------------------------------------------------------------------
// Phase 1: projection GEMM, MFMA bf16 (m97-style). M=768 exactly 6 tiles.
// ---------------------------------------------------------------------------
__global__ __launch_bounds__(256, 3)
void proj_kernel(const unsigned short* __restrict__ xb,   // [chunk][16384][256]
                 const unsigned short* __restrict__ Wb,   // [768][256]
                 unsigned short* __restrict__ qkv)        // [chunk*16384][768]
{
  __shared__ unsigned short As[128 * 64];
  __shared__ unsigned short Bs[128 * 64];

  const int tid = threadIdx.x;
  const int w = tid >> 6, lane = tid & 63;
  const int g16 = lane >> 4, l15 = lane & 15;
  const int m0 = blockIdx.x * 128;
  const int bl = blockIdx.y >> 7;
  const int p0 = (blockIdx.y & 127) * 128;
  const int wm = w >> 1, wn = w & 1;
  const unsigned short* xrow = xb + ((size_t)bl * HWPIX + p0) * CIN;

  f32x4 acc[4][4];
  #pragma unroll
  for (int i = 0; i < 4; ++i)
    #pragma unroll
    for (int j = 0; j < 4; ++j) acc[i][j] = (f32x4){0.f,0.f,0.f,0.f};

  for (int kk = 0; kk < 4; ++kk) {
    const int k0 = kk * 64;
    #pragma unroll
    for (int c = 0; c < 4; ++c) {
      int ci = w * 4 + c;
      gl_lds16(Wb   + (size_t)(m0 + ci*8 + (lane>>3)) * CIN + k0 + (lane&7)*8, As + ci*512);
      gl_lds16(xrow + (size_t)(     ci*8 + (lane>>3)) * CIN + k0 + (lane&7)*8, Bs + ci*512);
    }
    __syncthreads();

    #pragma unroll
    for (int kh = 0; kh < 2; ++kh) {
      bf16x8 af[4], bfr[4];
      #pragma unroll
      for (int t = 0; t < 4; ++t) {
        af[t]  = *(const bf16x8*)(As + (wm*64 + t*16 + l15)*64 + kh*32 + g16*8);
        bfr[t] = *(const bf16x8*)(Bs + (wn*64 + t*16 + l15)*64 + kh*32 + g16*8);
      }
      #pragma unroll
      for (int tm = 0; tm < 4; ++tm)
        #pragma unroll
        for (int tn = 0; tn < 4; ++tn)
          acc[tm][tn] = __builtin_amdgcn_mfma_f32_16x16x32_bf16(
                          af[tm], bfr[tn], acc[tm][tn], 0, 0, 0);
    }
    __syncthreads();
  }

  #pragma unroll
  for (int tm = 0; tm < 4; ++tm) {
    int ch = m0 + wm*64 + tm*16 + g16*4;
    #pragma unroll
    for (int tn = 0; tn < 4; ++tn) {
      int pix = p0 + wn*64 + tn*16 + l15;
      st_bf4(qkv + ((size_t)bl * HWPIX + pix) * MQKV + ch, acc[tm][tn]);
    }
  }
}

// ---------------------------------------------------------------------------
// Phase 2: fused halo attention, MFMA bf16, 3 blocks/CU (52608 B LDS).
// Bias computed in-kernel via 4 MFMAs from relb (staged transiently in Pq).
// ---------------------------------------------------------------------------
__global__ __launch_bounds__(256, 3)
void attn_kernel(const unsigned short* __restrict__ qkv,  // chunk base
                 const unsigned short* __restrict__ relb, // [64][32] bf16
                 float* __restrict__ out,                 // [4][256][128][128]
                 int b0)
{
  __shared__ unsigned short Ks[208 * KS_STRIDE];   // 14976 B [key][dh]
  __shared__ unsigned short Vt[32 * VT_STRIDE];    // 13568 B [dh][key]
  __shared__ unsigned short Pq[64 * PQ_STRIDE];    // 15360 B [q][key-in-half] (first 4KB = relb transient)
  __shared__ unsigned short QB[64 * QB_STRIDE];    //  8704 B [q][t_h 0..31 | t_w 32..63]

  const int tid = threadIdx.x;
  const int by = blockIdx.x >> 4, bx = blockIdx.x & 15;
  const int hd = blockIdx.y, bb = blockIdx.z;
  const size_t pixbase = (size_t)bb * HWPIX;

  const int w = tid >> 6, lane = tid & 63;
  const int g16 = lane >> 4, l15 = lane & 15;
  const int q = w * 16 + l15;
  const int qy = q >> 3, qx = q & 7;
  const int gy = by * BSZ + qy, gx = bx * BSZ + qx;

  // own q fragment (B-operand for both bias and QK MFMAs)
  bf16x8 qf = *(const bf16x8*)(qkv + (pixbase + (size_t)gy * IMG + gx) * MQKV + hd * 96 + g16 * 8);

  // relb -> Pq[0..2047]
  *(uint4*)(Pq + tid * 8) = *(const uint4*)(relb + tid * 8);

  // zero pads: Ks rows 196..207 (contiguous 432 shorts), Vt cols 196..211
  for (int i = tid; i < 432; i += 256) Ks[196 * KS_STRIDE + i] = 0;
  for (int i = tid; i < 512; i += 256) Vt[(i >> 4) * VT_STRIDE + 196 + (i & 15)] = 0;

  // stage K (rows, b64 pairs) and V (transposed scatter)
  for (int idx = tid; idx < NKEY * 8; idx += 256) {
    int key = idx >> 3, part = idx & 7;
    int ky = key / WIN, kx = key - ky * WIN;
    int sy = by * BSZ - HALO + ky, sx = bx * BSZ - HALO + kx;
    uint4 val = make_uint4(0,0,0,0);
    if ((unsigned)sy < (unsigned)IMG && (unsigned)sx < (unsigned)IMG)
      val = *(const uint4*)(qkv + (pixbase + sy * IMG + sx) * MQKV + hd * 96 + 32 + part * 8);
    if (part < 4) {
      unsigned short* kp = Ks + key * KS_STRIDE + part * 8;
      *(unsigned long long*)(kp    ) = (unsigned long long)val.x | ((unsigned long long)val.y << 32);
      *(unsigned long long*)(kp + 4) = (unsigned long long)val.z | ((unsigned long long)val.w << 32);
    } else {
      int dh0 = (part - 4) * 8;
      unsigned int u[4] = {val.x, val.y, val.z, val.w};
      #pragma unroll
      for (int e = 0; e < 4; ++e) {
        Vt[(dh0 + 2*e    ) * VT_STRIDE + key] = (unsigned short)(u[e] & 0xffffu);
        Vt[(dh0 + 2*e + 1) * VT_STRIDE + key] = (unsigned short)(u[e] >> 16);
      }
    }
  }
  __syncthreads();

  // ---- bias via MFMA: C[t][q] = rel[t] . q ----
  {
    const unsigned short* Hb = Pq;
    const unsigned short* Wr = Pq + 1024;
    bf16x8 ah0 = *(const bf16x8*)(Hb + l15 * 32 + g16 * 8);
    bf16x8 ah1 = *(const bf16x8*)(Hb + (16 + l15) * 32 + g16 * 8);
    bf16x8 aw0 = *(const bf16x8*)(Wr + l15 * 32 + g16 * 8);
    bf16x8 aw1 = *(const bf16x8*)(Wr + (16 + l15) * 32 + g16 * 8);
    f32x4 z = (f32x4){0.f,0.f,0.f,0.f};
    f32x4 ch0 = __builtin_amdgcn_mfma_f32_16x16x32_bf16(ah0, qf, z, 0, 0, 0);
    f32x4 ch1 = __builtin_amdgcn_mfma_f32_16x16x32_bf16(ah1, qf, z, 0, 0, 0);
    f32x4 cw0 = __builtin_amdgcn_mfma_f32_16x16x32_bf16(aw0, qf, z, 0, 0, 0);
    f32x4 cw1 = __builtin_amdgcn_mfma_f32_16x16x32_bf16(aw1, qf, z, 0, 0, 0);
    unsigned short* QBq = QB + q * QB_STRIDE;
    st_bf4(QBq      + g16 * 4, ch0);
    st_bf4(QBq + 16 + g16 * 4, ch1);
    st_bf4(QBq + 32 + g16 * 4, cw0);
    st_bf4(QBq + 48 + g16 * 4, cw1);
  }
  __syncthreads();   // all waves done reading relb region before Pq P-writes

  const unsigned short* QBq = QB + q * QB_STRIDE;
  unsigned short* Prow = Pq + q * PQ_STRIDE;

  float lsum = 0.f;
  f32x4 o0 = (f32x4){0.f,0.f,0.f,0.f}, o1 = (f32x4){0.f,0.f,0.f,0.f};
  const f32x4 z = (f32x4){0.f,0.f,0.f,0.f};

  #pragma unroll
  for (int half = 0; half < 2; ++half) {
    const int t0 = half ? 7 : 0;
    const int ntiles = half ? 6 : 7;
    #pragma unroll
    for (int u = 0; u < ntiles; ++u) {
      int nt = t0 + u;
      bf16x8 kf = ld2(Ks + (nt * 16 + l15) * KS_STRIDE + g16 * 8);
      f32x4 c = __builtin_amdgcn_mfma_f32_16x16x32_bf16(kf, qf, z, 0, 0, 0);
      float pv[4];
      #pragma unroll
      for (int i = 0; i < 4; ++i) {
        int key = nt * 16 + g16 * 4 + i;
        int ky = key / WIN, kx = key - ky * WIN;
        float s = c[i] * SCALE + bf2f(QBq[ky - qy + 13]) + bf2f(QBq[32 + kx - qx + 13]);
        float p = (key < NKEY) ? __expf(s) : 0.f;
        lsum += p;
        pv[i] = p;
      }
      ushort4 pk;
      pk.x = f2bf(pv[0]); pk.y = f2bf(pv[1]); pk.z = f2bf(pv[2]); pk.w = f2bf(pv[3]);
      *(ushort4*)(Prow + u * 16 + g16 * 4) = pk;
    }
    const int nch = half ? 3 : 4;
    #pragma unroll
    for (int cc = 0; cc < nch; ++cc) {
      bf16x8 pf = (bf16x8){0,0,0,0,0,0,0,0};
      bool masked = (half == 0 && cc == 3);     // keys 96..127: only 96..111 real
      if (!masked || g16 < 2)
        pf = *(const bf16x8*)(Prow + cc * 32 + g16 * 8);
      int vcol = (half ? 112 : 0) + cc * 32 + g16 * 8;
      bf16x8 v0 = ld2(Vt + l15 * VT_STRIDE + vcol);
      bf16x8 v1 = ld2(Vt + (16 + l15) * VT_STRIDE + vcol);
      o0 = __builtin_amdgcn_mfma_f32_16x16x32_bf16(v0, pf, o0, 0, 0, 0);
      o1 = __builtin_amdgcn_mfma_f32_16x16x32_bf16(v1, pf, o1, 0, 0, 0);
    }
  }

  lsum += __shfl_xor(lsum, 16);
  lsum += __shfl_xor(lsum, 32);
  float inv = 1.f / lsum;

  float* ob = out + (((size_t)(b0 + bb) * 256 + hd * DH) * HWPIX) + (size_t)gy * IMG + gx;
  #pragma unroll
  for (int i = 0; i < 4; ++i) {
    int dh0 = g16 * 4 + i;
    ob[(size_t)dh0 * HWPIX]        = o0[i] * inv;
    ob[(size_t)(dh0 + 16) * HWPIX] = o1[i] * inv;
  }
}

// ---------------------------------------------------------------------------
extern "C" void kernel_launch(void* const* d_in, const int* in_sizes, int n_in,
                              void* d_out, int out_size, void* d_ws, size_t ws_size,
                              hipStream_t stream)
{
  (void)in_sizes; (void)n_in; (void)out_size;
  const float* x    = (const float*)d_in[0];
  const float* wq   = (const float*)d_in[1];
  const float* wkv  = (const float*)d_in[2];
  const float* hrel = (const float*)d_in[3];
  const float* wrel = (const float*)d_in[4];
  float* out = (float*)d_out;

  const size_t wb_bytes   = (size_t)MQKV * CIN * 2;      // 393216
  const size_t relb_bytes = 4096;
  const size_t xb_per_b   = (size_t)HWPIX * CIN * 2;     // 8.39 MB
  const size_t qkv_per_b  = (size_t)HWPIX * MQKV * 2;    // 25.2 MB
  const int chunk = (ws_size >= wb_bytes + relb_bytes + 4 * (xb_per_b + qkv_per_b)) ? 4 : 1;

  unsigned short* Wb   = (unsigned short*)d_ws;
  unsigned short* relb = (unsigned short*)((char*)d_ws + wb_bytes);
  unsigned short* xb   = (unsigned short*)((char*)d_ws + wb_bytes + relb_bytes);
  unsigned short* qkv  = (unsigned short*)((char*)d_ws + wb_bytes + relb_bytes
                                           + (size_t)chunk * xb_per_b);

  convw_kernel<<<192, 256, 0, stream>>>(wq, wkv, Wb);
  convrel_kernel<<<8, 256, 0, stream>>>(hrel, wrel, relb);

  for (int b0 = 0; b0 < 4; b0 += chunk) {
    convx_kernel<<<dim3(256, chunk), 256, 0, stream>>>(x + (size_t)b0 * CIN * HWPIX, xb);
    proj_kernel<<<dim3(6, 128 * chunk), 256, 0, stream>>>(xb, Wb, qkv);
    attn_kernel<<<dim3(256, HEADS, chunk), 256, 0, stream>>>(qkv, relb, out, b0);
  }
}